// Round 6
// baseline (364.711 us; speedup 1.0000x reference)
//
#include <hip/hip_runtime.h>
#include <hip/hip_fp16.h>
#include <math.h>
#include <stdint.h>

// MSDeformAttn. N=2, C=256, M=8, L=4, P=4, D=32, LEN=21760
// R6: barrier-free direct-fragment MFMA for valproj/outproj (no LDS);
//     m-partitioned XCD-swizzled gather for L2 residency of value slices.

constexpr int NB  = 2;
constexpr int C   = 256;
constexpr int M   = 8;
constexpr int D   = 32;
constexpr int LEN = 21760;
constexpr int QCH = LEN / 4;   // 5440 queries per chunk (per batch)

typedef __attribute__((ext_vector_type(8))) short short8v;
typedef __attribute__((ext_vector_type(4))) float f32x4;

__device__ __forceinline__ short f2bf(float x) {
  uint32_t u = __float_as_uint(x);
  u = (u + 0x7fffu + ((u >> 16) & 1u)) >> 16;
  return (short)u;
}

// ---------------------------------------------------------------------------
// Prepack (all 4 weight mats in one launch): dst[c][k] = (bf16) src[k][c]
// ---------------------------------------------------------------------------
__global__ __launch_bounds__(256) void k_tcast4(
    const float* __restrict__ s0, const float* __restrict__ s1,
    const float* __restrict__ s2, const float* __restrict__ s3,
    short* __restrict__ d0, short* __restrict__ d1,
    short* __restrict__ d2, short* __restrict__ d3) {
  __shared__ float tile[32][33];
  const int z = blockIdx.z;
  const float* src = (z == 0) ? s0 : (z == 1) ? s1 : (z == 2) ? s2 : s3;
  short* dst = (z == 0) ? d0 : (z == 1) ? d1 : (z == 2) ? d2 : d3;
  const int ncols = (z == 2) ? 128 : 256;
  const int c0 = blockIdx.x * 32, k0 = blockIdx.y * 32;
  if (c0 >= ncols) return;
  const int t = threadIdx.x, tx = t & 31, ty = t >> 5;
#pragma unroll
  for (int i = 0; i < 4; ++i)
    tile[ty + i * 8][tx] = src[(size_t)(k0 + ty + i * 8) * ncols + c0 + tx];
  __syncthreads();
#pragma unroll
  for (int i = 0; i < 4; ++i)
    dst[(size_t)(c0 + ty + i * 8) * 256 + k0 + tx] = f2bf(tile[tx][ty + i * 8]);
}

// ---------------------------------------------------------------------------
// helpers: LDS staging for k_desc, B-fragment load from W^T
// ---------------------------------------------------------------------------
__device__ __forceinline__ void stage_cast(const float* __restrict__ p, char* sm, int t) {
  const int r = t >> 3, seg = t & 7;
  const float4* s = (const float4*)(p + (size_t)r * C + seg * 32);
  short v[32];
#pragma unroll
  for (int i = 0; i < 8; ++i) {
    float4 f = s[i];
    v[i * 4 + 0] = f2bf(f.x); v[i * 4 + 1] = f2bf(f.y);
    v[i * 4 + 2] = f2bf(f.z); v[i * 4 + 3] = f2bf(f.w);
  }
#pragma unroll
  for (int i = 0; i < 4; ++i) {
    const int kb = (seg * 32 + i * 8) * 2;
    *(int4*)(sm + r * 512 + (kb ^ ((r & 7) << 4))) = ((const int4*)v)[i];
  }
}

__device__ __forceinline__ short8v ldsA(const char* sm, int lane, int rt, int ks) {
  const int row = rt * 16 + (lane & 15);
  const int kb  = ks * 64 + ((lane >> 4) << 4);
  const int4 v = *(const int4*)(sm + row * 512 + (kb ^ ((row & 7) << 4)));
  union { int4 i; short8v s; } u; u.i = v; return u.s;
}

__device__ __forceinline__ short8v ldB(const short* __restrict__ WT, int col, int ks, int lane) {
  const int kidx = ks * 32 + ((lane >> 4) << 3);
  const int4 v = *(const int4*)(WT + (size_t)col * 256 + kidx);
  union { int4 i; short8v s; } u; u.i = v; return u.s;
}

// ---------------------------------------------------------------------------
// Kernel: value = bf16mm(input_flatten, WvT) + bv -> fp16 value[n][m][pix][d]
// Barrier-free: wave owns 32 rows x 128 cols; A direct from global.
// ---------------------------------------------------------------------------
__global__ __launch_bounds__(256, 4) void k_valproj(
    const float* __restrict__ infl, const short* __restrict__ WvT,
    const float* __restrict__ bv, __half* __restrict__ value) {
  const int t = threadIdx.x, lane = t & 63, w = t >> 6;
  const int r0 = blockIdx.x * 64 + (w & 1) * 32;
  const int c0 = (w >> 1) * 128;
  const int lr = lane & 15, lk = lane >> 4;

  f32x4 acc[2][8];
#pragma unroll
  for (int a = 0; a < 2; ++a)
#pragma unroll
    for (int b = 0; b < 8; ++b) acc[a][b] = (f32x4){0.f, 0.f, 0.f, 0.f};

#pragma unroll
  for (int ks = 0; ks < 8; ++ks) {
    short8v af[2];
#pragma unroll
    for (int rt = 0; rt < 2; ++rt) {
      const float* ap = infl + (size_t)(r0 + rt * 16 + lr) * C + ks * 32 + lk * 8;
      const float4 f0 = *(const float4*)ap;
      const float4 f1 = *(const float4*)(ap + 4);
      af[rt][0] = f2bf(f0.x); af[rt][1] = f2bf(f0.y);
      af[rt][2] = f2bf(f0.z); af[rt][3] = f2bf(f0.w);
      af[rt][4] = f2bf(f1.x); af[rt][5] = f2bf(f1.y);
      af[rt][6] = f2bf(f1.z); af[rt][7] = f2bf(f1.w);
    }
#pragma unroll
    for (int ct = 0; ct < 8; ++ct) {
      const short8v b = ldB(WvT, c0 + ct * 16 + lr, ks, lane);
      acc[0][ct] = __builtin_amdgcn_mfma_f32_16x16x32_bf16(af[0], b, acc[0][ct], 0, 0, 0);
      acc[1][ct] = __builtin_amdgcn_mfma_f32_16x16x32_bf16(af[1], b, acc[1][ct], 0, 0, 0);
    }
  }

  const int n = (blockIdx.x >= (LEN / 64)) ? 1 : 0;
  const int pixbase = r0 - n * LEN;
#pragma unroll
  for (int ct = 0; ct < 8; ++ct) {
    const int col = c0 + ct * 16 + lr;
    const float bb = bv[col];
    const int m = col >> 5, d = col & 31;
    __half* vp = value + ((size_t)(n * 8 + m) * LEN) * 32 + d;
#pragma unroll
    for (int rt = 0; rt < 2; ++rt)
#pragma unroll
      for (int r = 0; r < 4; ++r) {
        const int pix = pixbase + rt * 16 + lk * 4 + r;
        vp[(size_t)pix * 32] = __float2half(acc[rt][ct][r] + bb);
      }
  }
}

// ---------------------------------------------------------------------------
// Kernel: offsets/attn GEMM (bf16 MFMA) + softmax + descriptor build
// ---------------------------------------------------------------------------
__global__ __launch_bounds__(256, 3) void k_desc(
    const float* __restrict__ query, const float* __restrict__ refp,
    const short* __restrict__ WdT, const float* __restrict__ boff,
    const float* __restrict__ battn, uint4* __restrict__ descD, int qbase) {
  __shared__ __align__(16) char smem[50176];
  char*  smA  = smem;                       // [32][512] bf16 A-tile
  float* offs = (float*)smem;               // [32][256] (aliases smA; used later)
  float* attw = (float*)(smem + 32768);     // [32][128]
  float* refs = (float*)(smem + 49152);     // [32][8]

  const int t = threadIdx.x, lane = t & 63, w = t >> 6;
  const int n   = blockIdx.x / 170;
  const int q0c = (blockIdx.x % 170) * 32;
  const size_t qrow = (size_t)n * LEN + qbase + q0c;

  refs[t] = refp[qrow * 8 + t];
  stage_cast(query + qrow * C, smA, t);
  __syncthreads();

  f32x4 acc[2][6];
#pragma unroll
  for (int a = 0; a < 2; ++a)
#pragma unroll
    for (int b = 0; b < 6; ++b) acc[a][b] = (f32x4){0.f, 0.f, 0.f, 0.f};
  const int c0w = w * 96;
#pragma unroll
  for (int ks = 0; ks < 8; ++ks) {
    const short8v a0 = ldsA(smA, lane, 0, ks);
    const short8v a1 = ldsA(smA, lane, 1, ks);
#pragma unroll
    for (int ct = 0; ct < 6; ++ct) {
      const short8v b = ldB(WdT, c0w + ct * 16 + (lane & 15), ks, lane);
      acc[0][ct] = __builtin_amdgcn_mfma_f32_16x16x32_bf16(a0, b, acc[0][ct], 0, 0, 0);
      acc[1][ct] = __builtin_amdgcn_mfma_f32_16x16x32_bf16(a1, b, acc[1][ct], 0, 0, 0);
    }
  }
  __syncthreads();   // all LDS A reads complete before aliasing writes

#pragma unroll
  for (int ct = 0; ct < 6; ++ct) {
    const int col = c0w + ct * 16 + (lane & 15);
    const float bb = (col < 256) ? boff[col] : battn[col - 256];
#pragma unroll
    for (int rt = 0; rt < 2; ++rt)
#pragma unroll
      for (int r = 0; r < 4; ++r) {
        const int row = rt * 16 + ((lane >> 4) << 2) + r;
        const float vv = acc[rt][ct][r] + bb;
        if (col < 256) offs[row * 256 + col] = vv;
        else           attw[row * 128 + col - 256] = vv;
      }
  }
  __syncthreads();

  // softmax over 16 per (q, m): exactly 256 tasks
  {
    const int q = t >> 3, m = t & 7;
    float v[16], mx = -1e30f;
#pragma unroll
    for (int j = 0; j < 16; ++j) { v[j] = attw[q * 128 + m * 16 + j]; mx = fmaxf(mx, v[j]); }
    float s = 0.f;
#pragma unroll
    for (int j = 0; j < 16; ++j) { v[j] = __expf(v[j] - mx); s += v[j]; }
    const float inv = 1.f / s;
#pragma unroll
    for (int j = 0; j < 16; ++j) attw[q * 128 + m * 16 + j] = v[j] * inv;
  }
  __syncthreads();

  // descriptor build: 32 q x 128 = 4096, coalesced writes
  const size_t dbase = ((size_t)n * QCH + q0c) * 128;
#pragma unroll
  for (int i = 0; i < 16; ++i) {
    const int e = i * 256 + t;
    const int q = e >> 7, j8m = e & 127;
    const int m = j8m & 7, j = j8m >> 3, l = j >> 2;
    const int jo = m * 16 + j;
    const float ox = offs[q * 256 + 2 * jo], oy = offs[q * 256 + 2 * jo + 1];
    const float aw = attw[q * 128 + jo];
    const float rx = refs[q * 8 + l * 2 + 0], ry = refs[q * 8 + l * 2 + 1];
    const int W = 128 >> l;
    const int st_l = ((16384 - (16384 >> (2 * l))) * 4) / 3;  // 0,16384,20480,21504
    const float x = rx * (float)W + ox - 0.5f;
    const float y = ry * (float)W + oy - 0.5f;
    const float x0f = floorf(x), y0f = floorf(y);
    const float fx = x - x0f, fy = y - y0f;
    const int x0 = (int)x0f, y0 = (int)y0f;
    const int x1 = x0 + 1, y1 = y0 + 1;
    const int x0c = min(max(x0, 0), W - 1), x1c = min(max(x1, 0), W - 1);
    const int y0c = min(max(y0, 0), W - 1), y1c = min(max(y1, 0), W - 1);
    float wx0 = 1.f - fx, wx1 = fx, wy0 = 1.f - fy, wy1 = fy;
    if (x0 < 0 || x0 >= W) wx0 = 0.f;
    if (x1 < 0 || x1 >= W) wx1 = 0.f;
    if (y0 < 0 || y0 >= W) wy0 = 0.f;
    if (y1 < 0 || y1 >= W) wy1 = 0.f;
    uint4 dsc;
    dsc.x = (uint32_t)(st_l + y0c * W + x0c) | ((uint32_t)(st_l + y0c * W + x1c) << 16);
    dsc.y = (uint32_t)(st_l + y1c * W + x0c) | ((uint32_t)(st_l + y1c * W + x1c) << 16);
    union { __half2 h; uint32_t u; } p0, p1;
    p0.h = __floats2half2_rn(wx0 * wy0 * aw, wx1 * wy0 * aw);
    p1.h = __floats2half2_rn(wx0 * wy1 * aw, wx1 * wy1 * aw);
    dsc.z = p0.u;
    dsc.w = p1.u;
    descD[dbase + e] = dsc;
  }
}

// ---------------------------------------------------------------------------
// Kernel: pure gather, m-partitioned + XCD-swizzled.
// block = one (n,m) slice x 64 queries; bid%8 -> XCD; slice s%8 == bid%8
// so each XCD touches only value slices (0,m),(1,m): 2.78 MB -> L2-resident.
// ---------------------------------------------------------------------------
#define ACC4(RV, WW)                                        \
  {                                                         \
    const float2 f0 = __half22float2(RV.h[0]);              \
    const float2 f1 = __half22float2(RV.h[1]);              \
    const float2 f2 = __half22float2(RV.h[2]);              \
    const float2 f3 = __half22float2(RV.h[3]);              \
    a0 += (WW) * f0.x; a1 += (WW) * f0.y;                   \
    a2 += (WW) * f1.x; a3 += (WW) * f1.y;                   \
    a4 += (WW) * f2.x; a5 += (WW) * f2.y;                   \
    a6 += (WW) * f3.x; a7 += (WW) * f3.y;                   \
  }

__global__ __launch_bounds__(256, 8) void k_gather(
    const uint4* __restrict__ descD, const __half* __restrict__ value,
    short* __restrict__ accB, int qbase) {
  const int t = threadIdx.x;
  const int d4 = t & 3, ql = t >> 2;          // 64 queries per block
  const int bid = blockIdx.x;
  const int s = bid & 15, qc = bid >> 4;      // slice, query-chunk (85)
  const int n = s >> 3, m = s & 7;
  const int q = qc * 64 + ql;                 // within chunk
  const uint4* dp = descD + ((size_t)n * QCH + q) * 128 + m;
  const char* vb = (const char*)value +
                   (size_t)((n * 8 + m) * LEN) * 64 + d4 * 16;

  float a0 = 0.f, a1 = 0.f, a2 = 0.f, a3 = 0.f;
  float a4 = 0.f, a5 = 0.f, a6 = 0.f, a7 = 0.f;

#pragma unroll 4
  for (int j = 0; j < 16; ++j) {
    const uint4 dsc = dp[j * 8];
    const uint32_t i00 = dsc.x & 0xffffu, i01 = dsc.x >> 16;
    const uint32_t i10 = dsc.y & 0xffffu, i11 = dsc.y >> 16;
    union { uint32_t u; __half2 h; } pz, pw;
    pz.u = dsc.z; pw.u = dsc.w;
    const float2 wA = __half22float2(pz.h);
    const float2 wB = __half22float2(pw.h);
    union { uint4 v; __half2 h[4]; } r0, r1, r2, r3;
    r0.v = *(const uint4*)(vb + (size_t)i00 * 64u);
    r1.v = *(const uint4*)(vb + (size_t)i01 * 64u);
    r2.v = *(const uint4*)(vb + (size_t)i10 * 64u);
    r3.v = *(const uint4*)(vb + (size_t)i11 * 64u);
    ACC4(r0, wA.x);
    ACC4(r1, wA.y);
    ACC4(r2, wB.x);
    ACC4(r3, wB.y);
  }
  short8v o;
  o[0] = f2bf(a0); o[1] = f2bf(a1); o[2] = f2bf(a2); o[3] = f2bf(a3);
  o[4] = f2bf(a4); o[5] = f2bf(a5); o[6] = f2bf(a6); o[7] = f2bf(a7);
  *(short8v*)(accB + ((size_t)n * LEN + qbase + q) * 256 + m * 32 + d4 * 8) = o;
}

// ---------------------------------------------------------------------------
// Kernel: out = bf16mm(acc, WoT) + bo (fp32 out). Barrier-free, direct frags.
// ---------------------------------------------------------------------------
__global__ __launch_bounds__(256, 4) void k_outproj(
    const short* __restrict__ accB, const short* __restrict__ WoT,
    const float* __restrict__ bo, float* __restrict__ out) {
  const int t = threadIdx.x, lane = t & 63, w = t >> 6;
  const int r0 = blockIdx.x * 64 + (w & 1) * 32;
  const int c0 = (w >> 1) * 128;
  const int lr = lane & 15, lk = lane >> 4;

  f32x4 acc[2][8];
#pragma unroll
  for (int a = 0; a < 2; ++a)
#pragma unroll
    for (int b = 0; b < 8; ++b) acc[a][b] = (f32x4){0.f, 0.f, 0.f, 0.f};

#pragma unroll
  for (int ks = 0; ks < 8; ++ks) {
    short8v af[2];
#pragma unroll
    for (int rt = 0; rt < 2; ++rt) {
      const int4 v = *(const int4*)(accB + (size_t)(r0 + rt * 16 + lr) * C +
                                    ks * 32 + lk * 8);
      union { int4 i; short8v s; } u; u.i = v;
      af[rt] = u.s;
    }
#pragma unroll
    for (int ct = 0; ct < 8; ++ct) {
      const short8v b = ldB(WoT, c0 + ct * 16 + lr, ks, lane);
      acc[0][ct] = __builtin_amdgcn_mfma_f32_16x16x32_bf16(af[0], b, acc[0][ct], 0, 0, 0);
      acc[1][ct] = __builtin_amdgcn_mfma_f32_16x16x32_bf16(af[1], b, acc[1][ct], 0, 0, 0);
    }
  }

#pragma unroll
  for (int ct = 0; ct < 8; ++ct) {
    const int col = c0 + ct * 16 + lr;
    const float bb = bo[col];
#pragma unroll
    for (int rt = 0; rt < 2; ++rt)
#pragma unroll
      for (int r = 0; r < 4; ++r) {
        const int row = r0 + rt * 16 + lk * 4 + r;
        out[(size_t)row * C + col] = acc[rt][ct][r] + bb;
      }
  }
}

// ---------------------------------------------------------------------------
extern "C" void kernel_launch(void* const* d_in, const int* in_sizes, int n_in,
                              void* d_out, int out_size, void* d_ws, size_t ws_size,
                              hipStream_t stream) {
  const float* query = (const float*)d_in[0];
  const float* refp  = (const float*)d_in[1];
  const float* infl  = (const float*)d_in[2];
  const float* Woff  = (const float*)d_in[3];
  const float* boff  = (const float*)d_in[4];
  const float* Wattn = (const float*)d_in[5];
  const float* battn = (const float*)d_in[6];
  const float* Wval  = (const float*)d_in[7];
  const float* bval  = (const float*)d_in[8];
  const float* Wout  = (const float*)d_in[9];
  const float* bout  = (const float*)d_in[10];
  float* out = (float*)d_out;

  char* ws = (char*)d_ws;
  __half* value = (__half*)ws;                   // 22,282,240 B
  short*  accB  = (short*)(ws + 22282240);       // 22,282,240 B
  uint4*  descD = (uint4*)(ws + 44564480);       // 22,282,240 B
  short*  WvT   = (short*)(ws + 66846720);       // 131,072 B
  short*  WdT   = (short*)(ws + 66977792);       // 196,608 B
  short*  WoT   = (short*)(ws + 67174400);       // 131,072 B  (total 67.3 MB)

  k_tcast4<<<dim3(8, 8, 4), 256, 0, stream>>>(
      Wval, Woff, Wattn, Wout, WvT, WdT, WdT + (size_t)256 * 256, WoT);

  k_valproj<<<(NB * LEN) / 64, 256, 0, stream>>>(infl, WvT, bval, value);

  for (int c = 0; c < 4; ++c) {
    k_desc<<<2 * (QCH / 32), 256, 0, stream>>>(query, refp, WdT, boff, battn,
                                               descD, c * QCH);
    k_gather<<<16 * (QCH / 64), 256, 0, stream>>>(descD, value, accB, c * QCH);
  }

  k_outproj<<<(NB * LEN) / 64, 256, 0, stream>>>(accB, WoT, bout, out);
}

// Round 7
// 331.062 us; speedup vs baseline: 1.1016x; 1.1016x over previous
//
#include <hip/hip_runtime.h>
#include <hip/hip_fp16.h>
#include <math.h>
#include <stdint.h>

// MSDeformAttn. N=2, C=256, M=8, L=4, P=4, D=32, LEN=21760
// R7: slice-major descriptor layout (fixes R6 desc overfetch) + XCD-swizzled
//     m-partitioned gather; 16x256 wave tiles for valproj/outproj.

constexpr int NB  = 2;
constexpr int C   = 256;
constexpr int M   = 8;
constexpr int D   = 32;
constexpr int LEN = 21760;
constexpr int QCH = LEN / 4;   // 5440 queries per chunk (per batch)

typedef __attribute__((ext_vector_type(8))) short short8v;
typedef __attribute__((ext_vector_type(4))) float f32x4;

__device__ __forceinline__ short f2bf(float x) {
  uint32_t u = __float_as_uint(x);
  u = (u + 0x7fffu + ((u >> 16) & 1u)) >> 16;
  return (short)u;
}

// ---------------------------------------------------------------------------
// Prepack (all 4 weight mats in one launch): dst[c][k] = (bf16) src[k][c]
// ---------------------------------------------------------------------------
__global__ __launch_bounds__(256) void k_tcast4(
    const float* __restrict__ s0, const float* __restrict__ s1,
    const float* __restrict__ s2, const float* __restrict__ s3,
    short* __restrict__ d0, short* __restrict__ d1,
    short* __restrict__ d2, short* __restrict__ d3) {
  __shared__ float tile[32][33];
  const int z = blockIdx.z;
  const float* src = (z == 0) ? s0 : (z == 1) ? s1 : (z == 2) ? s2 : s3;
  short* dst = (z == 0) ? d0 : (z == 1) ? d1 : (z == 2) ? d2 : d3;
  const int ncols = (z == 2) ? 128 : 256;
  const int c0 = blockIdx.x * 32, k0 = blockIdx.y * 32;
  if (c0 >= ncols) return;
  const int t = threadIdx.x, tx = t & 31, ty = t >> 5;
#pragma unroll
  for (int i = 0; i < 4; ++i)
    tile[ty + i * 8][tx] = src[(size_t)(k0 + ty + i * 8) * ncols + c0 + tx];
  __syncthreads();
#pragma unroll
  for (int i = 0; i < 4; ++i)
    dst[(size_t)(c0 + ty + i * 8) * 256 + k0 + tx] = f2bf(tile[tx][ty + i * 8]);
}

// ---------------------------------------------------------------------------
// helpers
// ---------------------------------------------------------------------------
__device__ __forceinline__ void stage_cast(const float* __restrict__ p, char* sm, int t) {
  const int r = t >> 3, seg = t & 7;
  const float4* s = (const float4*)(p + (size_t)r * C + seg * 32);
  short v[32];
#pragma unroll
  for (int i = 0; i < 8; ++i) {
    float4 f = s[i];
    v[i * 4 + 0] = f2bf(f.x); v[i * 4 + 1] = f2bf(f.y);
    v[i * 4 + 2] = f2bf(f.z); v[i * 4 + 3] = f2bf(f.w);
  }
#pragma unroll
  for (int i = 0; i < 4; ++i) {
    const int kb = (seg * 32 + i * 8) * 2;
    *(int4*)(sm + r * 512 + (kb ^ ((r & 7) << 4))) = ((const int4*)v)[i];
  }
}

__device__ __forceinline__ short8v ldsA(const char* sm, int lane, int rt, int ks) {
  const int row = rt * 16 + (lane & 15);
  const int kb  = ks * 64 + ((lane >> 4) << 4);
  const int4 v = *(const int4*)(sm + row * 512 + (kb ^ ((row & 7) << 4)));
  union { int4 i; short8v s; } u; u.i = v; return u.s;
}

__device__ __forceinline__ short8v ldB(const short* __restrict__ WT, int col, int ks, int lane) {
  const int kidx = ks * 32 + ((lane >> 4) << 3);
  const int4 v = *(const int4*)(WT + (size_t)col * 256 + kidx);
  union { int4 i; short8v s; } u; u.i = v; return u.s;
}

// ---------------------------------------------------------------------------
// Kernel: value = bf16mm(input_flatten, WvT) + bv -> fp16 value[n][m][pix][d]
// Barrier-free; wave owns 16 rows x 256 cols (A rows loaded once per block).
// ---------------------------------------------------------------------------
__global__ __launch_bounds__(256, 4) void k_valproj(
    const float* __restrict__ infl, const short* __restrict__ WvT,
    const float* __restrict__ bv, __half* __restrict__ value) {
  const int t = threadIdx.x, lane = t & 63, w = t >> 6;
  const int r0 = blockIdx.x * 64 + w * 16;
  const int lr = lane & 15, lk = lane >> 4;

  f32x4 acc[16];
#pragma unroll
  for (int b = 0; b < 16; ++b) acc[b] = (f32x4){0.f, 0.f, 0.f, 0.f};

#pragma unroll
  for (int ks = 0; ks < 8; ++ks) {
    const float* ap = infl + (size_t)(r0 + lr) * C + ks * 32 + lk * 8;
    const float4 f0 = *(const float4*)ap;
    const float4 f1 = *(const float4*)(ap + 4);
    short8v af;
    af[0] = f2bf(f0.x); af[1] = f2bf(f0.y);
    af[2] = f2bf(f0.z); af[3] = f2bf(f0.w);
    af[4] = f2bf(f1.x); af[5] = f2bf(f1.y);
    af[6] = f2bf(f1.z); af[7] = f2bf(f1.w);
#pragma unroll
    for (int ct = 0; ct < 16; ++ct) {
      const short8v b = ldB(WvT, ct * 16 + lr, ks, lane);
      acc[ct] = __builtin_amdgcn_mfma_f32_16x16x32_bf16(af, b, acc[ct], 0, 0, 0);
    }
  }

  const int n = (blockIdx.x >= (LEN / 64)) ? 1 : 0;
  const int pixbase = r0 - n * LEN;
#pragma unroll
  for (int ct = 0; ct < 16; ++ct) {
    const int col = ct * 16 + lr;
    const float bb = bv[col];
    const int m = col >> 5, d = col & 31;
    __half* vp = value + ((size_t)(n * 8 + m) * LEN) * 32 + d;
#pragma unroll
    for (int r = 0; r < 4; ++r) {
      const int pix = pixbase + lk * 4 + r;
      vp[(size_t)pix * 32] = __float2half(acc[ct][r] + bb);
    }
  }
}

// ---------------------------------------------------------------------------
// Kernel: offsets/attn GEMM (bf16 MFMA) + softmax + descriptor build
// Desc layout: descD[((n*8+m)*QCH + q)*16 + j]  (slice-major!)
// ---------------------------------------------------------------------------
__global__ __launch_bounds__(256, 3) void k_desc(
    const float* __restrict__ query, const float* __restrict__ refp,
    const short* __restrict__ WdT, const float* __restrict__ boff,
    const float* __restrict__ battn, uint4* __restrict__ descD, int qbase) {
  __shared__ __align__(16) char smem[50176];
  char*  smA  = smem;                       // [32][512] bf16 A-tile
  float* offs = (float*)smem;               // [32][256] (aliases smA; used later)
  float* attw = (float*)(smem + 32768);     // [32][128]
  float* refs = (float*)(smem + 49152);     // [32][8]

  const int t = threadIdx.x, lane = t & 63, w = t >> 6;
  const int n   = blockIdx.x / 170;
  const int q0c = (blockIdx.x % 170) * 32;
  const size_t qrow = (size_t)n * LEN + qbase + q0c;

  refs[t] = refp[qrow * 8 + t];
  stage_cast(query + qrow * C, smA, t);
  __syncthreads();

  f32x4 acc[2][6];
#pragma unroll
  for (int a = 0; a < 2; ++a)
#pragma unroll
    for (int b = 0; b < 6; ++b) acc[a][b] = (f32x4){0.f, 0.f, 0.f, 0.f};
  const int c0w = w * 96;
#pragma unroll
  for (int ks = 0; ks < 8; ++ks) {
    const short8v a0 = ldsA(smA, lane, 0, ks);
    const short8v a1 = ldsA(smA, lane, 1, ks);
#pragma unroll
    for (int ct = 0; ct < 6; ++ct) {
      const short8v b = ldB(WdT, c0w + ct * 16 + (lane & 15), ks, lane);
      acc[0][ct] = __builtin_amdgcn_mfma_f32_16x16x32_bf16(a0, b, acc[0][ct], 0, 0, 0);
      acc[1][ct] = __builtin_amdgcn_mfma_f32_16x16x32_bf16(a1, b, acc[1][ct], 0, 0, 0);
    }
  }
  __syncthreads();   // all LDS A reads complete before aliasing writes

#pragma unroll
  for (int ct = 0; ct < 6; ++ct) {
    const int col = c0w + ct * 16 + (lane & 15);
    const float bb = (col < 256) ? boff[col] : battn[col - 256];
#pragma unroll
    for (int rt = 0; rt < 2; ++rt)
#pragma unroll
      for (int r = 0; r < 4; ++r) {
        const int row = rt * 16 + ((lane >> 4) << 2) + r;
        const float vv = acc[rt][ct][r] + bb;
        if (col < 256) offs[row * 256 + col] = vv;
        else           attw[row * 128 + col - 256] = vv;
      }
  }
  __syncthreads();

  // softmax over 16 per (q, m): exactly 256 tasks
  {
    const int q = t >> 3, m = t & 7;
    float v[16], mx = -1e30f;
#pragma unroll
    for (int j = 0; j < 16; ++j) { v[j] = attw[q * 128 + m * 16 + j]; mx = fmaxf(mx, v[j]); }
    float s = 0.f;
#pragma unroll
    for (int j = 0; j < 16; ++j) { v[j] = __expf(v[j] - mx); s += v[j]; }
    const float inv = 1.f / s;
#pragma unroll
    for (int j = 0; j < 16; ++j) attw[q * 128 + m * 16 + j] = v[j] * inv;
  }
  __syncthreads();

  // descriptor build: e = q*128 + m*16 + j  -> descD[((n*8+m)*QCH+q)*16+j]
#pragma unroll
  for (int i = 0; i < 16; ++i) {
    const int e = i * 256 + t;
    const int q = e >> 7, rem = e & 127;
    const int m = rem >> 4, j = rem & 15, l = j >> 2;
    const int jo = m * 16 + j;
    const float ox = offs[q * 256 + 2 * jo], oy = offs[q * 256 + 2 * jo + 1];
    const float aw = attw[q * 128 + jo];
    const float rx = refs[q * 8 + l * 2 + 0], ry = refs[q * 8 + l * 2 + 1];
    const int W = 128 >> l;
    const int st_l = ((16384 - (16384 >> (2 * l))) * 4) / 3;  // 0,16384,20480,21504
    const float x = rx * (float)W + ox - 0.5f;
    const float y = ry * (float)W + oy - 0.5f;
    const float x0f = floorf(x), y0f = floorf(y);
    const float fx = x - x0f, fy = y - y0f;
    const int x0 = (int)x0f, y0 = (int)y0f;
    const int x1 = x0 + 1, y1 = y0 + 1;
    const int x0c = min(max(x0, 0), W - 1), x1c = min(max(x1, 0), W - 1);
    const int y0c = min(max(y0, 0), W - 1), y1c = min(max(y1, 0), W - 1);
    float wx0 = 1.f - fx, wx1 = fx, wy0 = 1.f - fy, wy1 = fy;
    if (x0 < 0 || x0 >= W) wx0 = 0.f;
    if (x1 < 0 || x1 >= W) wx1 = 0.f;
    if (y0 < 0 || y0 >= W) wy0 = 0.f;
    if (y1 < 0 || y1 >= W) wy1 = 0.f;
    uint4 dsc;
    dsc.x = (uint32_t)(st_l + y0c * W + x0c) | ((uint32_t)(st_l + y0c * W + x1c) << 16);
    dsc.y = (uint32_t)(st_l + y1c * W + x0c) | ((uint32_t)(st_l + y1c * W + x1c) << 16);
    union { __half2 h; uint32_t u; } p0, p1;
    p0.h = __floats2half2_rn(wx0 * wy0 * aw, wx1 * wy0 * aw);
    p1.h = __floats2half2_rn(wx0 * wy1 * aw, wx1 * wy1 * aw);
    dsc.z = p0.u;
    dsc.w = p1.u;
    descD[((size_t)(n * 8 + m) * QCH + q0c + q) * 16 + j] = dsc;
  }
}

// ---------------------------------------------------------------------------
// Kernel: pure gather, m-partitioned + XCD-swizzled, slice-major desc.
// block = one (n,m) slice x 64 queries; desc reads fully contiguous.
// ---------------------------------------------------------------------------
#define ACC4(RV, WW)                                        \
  {                                                         \
    const float2 f0 = __half22float2(RV.h[0]);              \
    const float2 f1 = __half22float2(RV.h[1]);              \
    const float2 f2 = __half22float2(RV.h[2]);              \
    const float2 f3 = __half22float2(RV.h[3]);              \
    a0 += (WW) * f0.x; a1 += (WW) * f0.y;                   \
    a2 += (WW) * f1.x; a3 += (WW) * f1.y;                   \
    a4 += (WW) * f2.x; a5 += (WW) * f2.y;                   \
    a6 += (WW) * f3.x; a7 += (WW) * f3.y;                   \
  }

__global__ __launch_bounds__(256, 8) void k_gather(
    const uint4* __restrict__ descD, const __half* __restrict__ value,
    short* __restrict__ accB, int qbase) {
  const int t = threadIdx.x;
  const int d4 = t & 3, ql = t >> 2;          // 64 queries per block
  const int bid = blockIdx.x;
  const int s = bid & 15, qc = bid >> 4;      // slice, query-chunk (85)
  const int n = s >> 3, m = s & 7;
  const int q = qc * 64 + ql;                 // within chunk
  const uint4* dp = descD + ((size_t)(n * 8 + m) * QCH + q) * 16;
  const char* vb = (const char*)value +
                   (size_t)((n * 8 + m) * LEN) * 64 + d4 * 16;

  float a0 = 0.f, a1 = 0.f, a2 = 0.f, a3 = 0.f;
  float a4 = 0.f, a5 = 0.f, a6 = 0.f, a7 = 0.f;

#pragma unroll 4
  for (int j = 0; j < 16; ++j) {
    const uint4 dsc = dp[j];
    const uint32_t i00 = dsc.x & 0xffffu, i01 = dsc.x >> 16;
    const uint32_t i10 = dsc.y & 0xffffu, i11 = dsc.y >> 16;
    union { uint32_t u; __half2 h; } pz, pw;
    pz.u = dsc.z; pw.u = dsc.w;
    const float2 wA = __half22float2(pz.h);
    const float2 wB = __half22float2(pw.h);
    union { uint4 v; __half2 h[4]; } r0, r1, r2, r3;
    r0.v = *(const uint4*)(vb + (size_t)i00 * 64u);
    r1.v = *(const uint4*)(vb + (size_t)i01 * 64u);
    r2.v = *(const uint4*)(vb + (size_t)i10 * 64u);
    r3.v = *(const uint4*)(vb + (size_t)i11 * 64u);
    ACC4(r0, wA.x);
    ACC4(r1, wA.y);
    ACC4(r2, wB.x);
    ACC4(r3, wB.y);
  }
  short8v o;
  o[0] = f2bf(a0); o[1] = f2bf(a1); o[2] = f2bf(a2); o[3] = f2bf(a3);
  o[4] = f2bf(a4); o[5] = f2bf(a5); o[6] = f2bf(a6); o[7] = f2bf(a7);
  *(short8v*)(accB + ((size_t)n * LEN + qbase + q) * 256 + m * 32 + d4 * 8) = o;
}

// ---------------------------------------------------------------------------
// Kernel: out = bf16mm(acc, WoT) + bo (fp32 out). Barrier-free, 16x256 waves.
// ---------------------------------------------------------------------------
__global__ __launch_bounds__(256, 4) void k_outproj(
    const short* __restrict__ accB, const short* __restrict__ WoT,
    const float* __restrict__ bo, float* __restrict__ out) {
  const int t = threadIdx.x, lane = t & 63, w = t >> 6;
  const int r0 = blockIdx.x * 64 + w * 16;
  const int lr = lane & 15, lk = lane >> 4;

  f32x4 acc[16];
#pragma unroll
  for (int b = 0; b < 16; ++b) acc[b] = (f32x4){0.f, 0.f, 0.f, 0.f};

#pragma unroll
  for (int ks = 0; ks < 8; ++ks) {
    const int4 v = *(const int4*)(accB + (size_t)(r0 + lr) * C + ks * 32 + lk * 8);
    union { int4 i; short8v s; } u; u.i = v;
    const short8v af = u.s;
#pragma unroll
    for (int ct = 0; ct < 16; ++ct) {
      const short8v b = ldB(WoT, ct * 16 + lr, ks, lane);
      acc[ct] = __builtin_amdgcn_mfma_f32_16x16x32_bf16(af, b, acc[ct], 0, 0, 0);
    }
  }

#pragma unroll
  for (int ct = 0; ct < 16; ++ct) {
    const int col = ct * 16 + lr;
    const float bb = bo[col];
#pragma unroll
    for (int r = 0; r < 4; ++r) {
      const int row = r0 + lk * 4 + r;
      out[(size_t)row * C + col] = acc[ct][r] + bb;
    }
  }
}

// ---------------------------------------------------------------------------
extern "C" void kernel_launch(void* const* d_in, const int* in_sizes, int n_in,
                              void* d_out, int out_size, void* d_ws, size_t ws_size,
                              hipStream_t stream) {
  const float* query = (const float*)d_in[0];
  const float* refp  = (const float*)d_in[1];
  const float* infl  = (const float*)d_in[2];
  const float* Woff  = (const float*)d_in[3];
  const float* boff  = (const float*)d_in[4];
  const float* Wattn = (const float*)d_in[5];
  const float* battn = (const float*)d_in[6];
  const float* Wval  = (const float*)d_in[7];
  const float* bval  = (const float*)d_in[8];
  const float* Wout  = (const float*)d_in[9];
  const float* bout  = (const float*)d_in[10];
  float* out = (float*)d_out;

  char* ws = (char*)d_ws;
  __half* value = (__half*)ws;                   // 22,282,240 B
  short*  accB  = (short*)(ws + 22282240);       // 22,282,240 B
  uint4*  descD = (uint4*)(ws + 44564480);       // 22,282,240 B
  short*  WvT   = (short*)(ws + 66846720);       // 131,072 B
  short*  WdT   = (short*)(ws + 66977792);       // 196,608 B
  short*  WoT   = (short*)(ws + 67174400);       // 131,072 B  (total 67.3 MB)

  k_tcast4<<<dim3(8, 8, 4), 256, 0, stream>>>(
      Wval, Woff, Wattn, Wout, WvT, WdT, WdT + (size_t)256 * 256, WoT);

  k_valproj<<<(NB * LEN) / 64, 256, 0, stream>>>(infl, WvT, bval, value);

  for (int c = 0; c < 4; ++c) {
    k_desc<<<2 * (QCH / 32), 256, 0, stream>>>(query, refp, WdT, boff, battn,
                                               descD, c * QCH);
    k_gather<<<16 * (QCH / 64), 256, 0, stream>>>(descD, value, accB, c * QCH);
  }

  k_outproj<<<(NB * LEN) / 64, 256, 0, stream>>>(accB, WoT, bout, out);
}